// Round 3
// baseline (1603.523 us; speedup 1.0000x reference)
//
#include <hip/hip_runtime.h>
#include <math.h>

#define NB   4
#define NT   500
#define NF   65
#define NC   128
#define NH   8
#define NE   4
#define NV   16
#define NCTX 10
#define DQ   260    // NF*NE
#define DV   1040   // NF*NV
#define DP   8320   // NF*NC

// murs layout offsets (floats): [muQ rsQ muK rsK muV rsV], each 32*500
#define MQ 0
#define RQ 16000
#define MK 32000
#define RK 48000
#define MV 64000
#define RV 80000

// load 8 consecutive-c float2 x values; stride between c rows = NF*NT floats
#define LOADX(buf, c0) { _Pragma("unroll") for (int j = 0; j < 8; j++) \
    buf[j] = *(const float2*)(xp + (size_t)((c0) + j) * (NF * NT)); }

// ---------------- Q/K projection: 128 -> 32, PReLU, [bh][d=f*4+e][t]; atomic LN stats ----------------
__global__ __launch_bounds__(256) void proj32_k(const float* __restrict__ x,
    const float* __restrict__ W, const float* __restrict__ bias,
    const float* __restrict__ a, float* __restrict__ out,
    float* __restrict__ sS, float* __restrict__ sS2)
{
    int b = blockIdx.x / NF, f = blockIdx.x % NF;
    int t0 = 2 * threadIdx.x;
    if (t0 >= NT) return;
    const float* xp = x + ((size_t)(b * NC) * NF + f) * NT + t0;
    float2 acc[32];
#pragma unroll
    for (int o = 0; o < 32; o++) acc[o] = make_float2(0.f, 0.f);
#define FMAS32(buf, c0) { _Pragma("unroll") for (int o = 0; o < 32; o++) { \
    _Pragma("unroll") for (int j = 0; j < 8; j++) { \
        float w = W[o * NC + (c0) + j]; \
        acc[o].x += buf[j].x * w; acc[o].y += buf[j].y * w; } } }
    float2 xa[8], xb[8];
    LOADX(xa, 0)
#pragma unroll
    for (int c0 = 0; c0 < NC; c0 += 16) {
        LOADX(xb, c0 + 8)
        FMAS32(xa, c0)
        if (c0 + 16 < NC) LOADX(xa, c0 + 16)
        FMAS32(xb, c0 + 8)
    }
    float av = a[0];
#pragma unroll
    for (int o = 0; o < 32; o++) {
        float vx = acc[o].x + bias[o], vy = acc[o].y + bias[o];
        vx = vx >= 0.f ? vx : av * vx;
        vy = vy >= 0.f ? vy : av * vy;
        acc[o].x = vx; acc[o].y = vy;
        int h = o >> 2, e = o & 3;
        *(float2*)(out + ((size_t)(b * NH + h) * DQ + f * NE + e) * NT + t0) = acc[o];
    }
#pragma unroll
    for (int h = 0; h < NH; h++) {
        float sx = 0.f, sy = 0.f, qx = 0.f, qy = 0.f;
#pragma unroll
        for (int e = 0; e < 4; e++) {
            float2 v = acc[h * 4 + e];
            sx += v.x; sy += v.y; qx += v.x * v.x; qy += v.y * v.y;
        }
        int base = (b * NH + h) * NT + t0;
        atomicAdd(&sS[base], sx);      atomicAdd(&sS[base + 1], sy);
        atomicAdd(&sS2[base], qx);     atomicAdd(&sS2[base + 1], qy);
    }
}

// ---------------- V projection: 128 -> 128 (64/block), PReLU, [bh][d=f*16+v][t]; atomic LN stats ----------------
__global__ __launch_bounds__(256) void projV_k(const float* __restrict__ x,
    const float* __restrict__ W, const float* __restrict__ bias,
    const float* __restrict__ a, float* __restrict__ out,
    float* __restrict__ sS, float* __restrict__ sS2)
{
    int b = blockIdx.x / NF, f = blockIdx.x % NF;
    int o0 = blockIdx.y * 64;
    int t0 = 2 * threadIdx.x;
    if (t0 >= NT) return;
    const float* xp = x + ((size_t)(b * NC) * NF + f) * NT + t0;
    float2 acc[64];
#pragma unroll
    for (int o = 0; o < 64; o++) acc[o] = make_float2(0.f, 0.f);
#define FMAS64(buf, c0) { _Pragma("unroll") for (int o = 0; o < 64; o++) { \
    _Pragma("unroll") for (int j = 0; j < 8; j++) { \
        float w = W[(o0 + o) * NC + (c0) + j]; \
        acc[o].x += buf[j].x * w; acc[o].y += buf[j].y * w; } } }
    float2 xa[8], xb[8];
    LOADX(xa, 0)
#pragma unroll
    for (int c0 = 0; c0 < NC; c0 += 16) {
        LOADX(xb, c0 + 8)
        FMAS64(xa, c0)
        if (c0 + 16 < NC) LOADX(xa, c0 + 16)
        FMAS64(xb, c0 + 8)
    }
    float av = a[0];
#pragma unroll
    for (int o = 0; o < 64; o++) {
        int oo = o0 + o;
        float vx = acc[o].x + bias[oo], vy = acc[o].y + bias[oo];
        vx = vx >= 0.f ? vx : av * vx;
        vy = vy >= 0.f ? vy : av * vy;
        acc[o].x = vx; acc[o].y = vy;
        int h = oo >> 4, v = oo & 15;
        *(float2*)(out + ((size_t)(b * NH + h) * DV + f * NV + v) * NT + t0) = acc[o];
    }
#pragma unroll
    for (int hh = 0; hh < 4; hh++) {
        int h = (o0 >> 4) + hh;
        float sx = 0.f, sy = 0.f, qx = 0.f, qy = 0.f;
#pragma unroll
        for (int v = 0; v < 16; v++) {
            float2 vv = acc[hh * 16 + v];
            sx += vv.x; sy += vv.y; qx += vv.x * vv.x; qy += vv.y * vv.y;
        }
        int base = (b * NH + h) * NT + t0;
        atomicAdd(&sS[base], sx);      atomicAdd(&sS[base + 1], sy);
        atomicAdd(&sS2[base], qx);     atomicAdd(&sS2[base + 1], qy);
    }
}

// ---------------- P projection: VoT 128 -> 128 (64/block), PReLU, yraw[b][o][f][t]; atomic final-LN stats ----------------
__global__ __launch_bounds__(256) void projP_k(const float* __restrict__ VoT,
    const float* __restrict__ W, const float* __restrict__ bias,
    const float* __restrict__ a, float* __restrict__ yraw,
    float* __restrict__ sP, float* __restrict__ s2P)
{
    int b = blockIdx.x / NF, f = blockIdx.x % NF;
    int o0 = blockIdx.y * 64;
    int t0 = 2 * threadIdx.x;
    if (t0 >= NT) return;
    float2 acc[64];
#pragma unroll
    for (int o = 0; o < 64; o++) acc[o] = make_float2(0.f, 0.f);
#define LOADZ(buf, c0) { int h_ = (c0) >> 4; int v0_ = (c0) & 15; \
    const float* zp = VoT + ((size_t)(b * NH + h_) * DV + f * NV + v0_) * NT + t0; \
    _Pragma("unroll") for (int j = 0; j < 8; j++) buf[j] = *(const float2*)(zp + (size_t)j * NT); }
    float2 xa[8], xb[8];
    LOADZ(xa, 0)
#pragma unroll
    for (int c0 = 0; c0 < NC; c0 += 16) {
        LOADZ(xb, c0 + 8)
        FMAS64(xa, c0)
        if (c0 + 16 < NC) LOADZ(xa, c0 + 16)
        FMAS64(xb, c0 + 8)
    }
    float av = a[0];
    float sx = 0.f, sy = 0.f, qx = 0.f, qy = 0.f;
#pragma unroll
    for (int o = 0; o < 64; o++) {
        int oo = o0 + o;
        float vx = acc[o].x + bias[oo], vy = acc[o].y + bias[oo];
        vx = vx >= 0.f ? vx : av * vx;
        vy = vy >= 0.f ? vy : av * vy;
        acc[o].x = vx; acc[o].y = vy;
        *(float2*)(yraw + ((size_t)(b * NC + oo) * NF + f) * NT + t0) = acc[o];
        sx += vx; sy += vy; qx += vx * vx; qy += vy * vy;
    }
    int base = b * NT + t0;
    atomicAdd(&sP[base], sx);      atomicAdd(&sP[base + 1], sy);
    atomicAdd(&s2P[base], qx);     atomicAdd(&s2P[base + 1], qy);
}

// ---------------- finalize QKV stats -> mu/rs ----------------
__global__ __launch_bounds__(256) void finqkv_k(const float* __restrict__ stats,
    float* __restrict__ murs)
{
    int i = blockIdx.x * 256 + threadIdx.x;
    if (i >= 48000) return;
    int seg = i / 16000, j = i % 16000;
    float S = stats[seg * 32000 + j], S2 = stats[seg * 32000 + 16000 + j];
    float D = (seg < 2) ? 260.f : 1040.f;
    float mu = S / D;
    float var = S2 / D - mu * mu;
    murs[seg * 32000 + j] = mu;
    murs[seg * 32000 + 16000 + j] = rsqrtf(var + 1e-5f);
}

__global__ __launch_bounds__(256) void finp_k(const float* __restrict__ sP,
    const float* __restrict__ s2P, float* __restrict__ muP, float* __restrict__ rsP)
{
    int i = blockIdx.x * 256 + threadIdx.x;
    if (i >= NB * NT) return;
    float inv = 1.0f / (float)DP;
    float mu = sP[i] * inv;
    float var = s2P[i] * inv - mu * mu;
    muP[i] = mu;
    rsP[i] = rsqrtf(var + 1e-5f);
}

// ---------------- K_buf_new / V_buf_new: LN applied on the fly ----------------
__global__ void copybuf_k(const float* __restrict__ Kt, const float* __restrict__ Vt,
    const float* __restrict__ murs,
    const float* __restrict__ g_K, const float* __restrict__ be_K,
    const float* __restrict__ g_V, const float* __restrict__ be_V,
    float* __restrict__ outK, float* __restrict__ outV)
{
    int i = blockIdx.x * 256 + threadIdx.x;
    const int NK = 32 * 9 * DQ;
    const int NVb = 32 * 9 * DV;
    if (i < NK) {
        int bh = i / (9 * DQ); int r = i % (9 * DQ); int j = r / DQ; int d = r % DQ;
        int tt = 491 + j;
        float v = Kt[(size_t)(bh * DQ + d) * NT + tt];
        float mu = murs[MK + bh * NT + tt], rs = murs[RK + bh * NT + tt];
        outK[i] = (v - mu) * rs * g_K[d] + be_K[d];
    } else if (i < NK + NVb) {
        int i2 = i - NK;
        int bh = i2 / (9 * DV); int r = i2 % (9 * DV); int j = r / DV; int d = r % DV;
        int tt = 491 + j;
        float v = Vt[(size_t)(bh * DV + d) * NT + tt];
        float mu = murs[MV + bh * NT + tt], rs = murs[RV + bh * NT + tt];
        outV[i2] = (v - mu) * rs * g_V[d] + be_V[d];
    }
}

// ---------------- scores partials (LN fused): spart[ch][bh][c][t] ----------------
__global__ __launch_bounds__(256) void scores_s1_k(const float* __restrict__ Qt,
    const float* __restrict__ Kt, const float* __restrict__ Kbuf,
    const float* __restrict__ murs,
    const float* __restrict__ g_Q, const float* __restrict__ be_Q,
    const float* __restrict__ g_K, const float* __restrict__ be_K,
    float* __restrict__ spart)
{
    int bh = blockIdx.x;
    int t = blockIdx.y * 256 + threadIdx.x;
    if (t >= NT) return;
    int z = blockIdx.z;
    int d0 = z * 52;
    float rsq = murs[RQ + bh * NT + t];
    float mq = -murs[MQ + bh * NT + t] * rsq;
    float s[NCTX];
    if (t >= NCTX - 1) {
        float rkc[NCTX], mkc[NCTX];
#pragma unroll
        for (int c = 0; c < NCTX; c++) {
            int tk = t - (NCTX - 1) + c;
            rkc[c] = murs[RK + bh * NT + tk];
            mkc[c] = -murs[MK + bh * NT + tk] * rkc[c];
        }
        float A[NCTX], SG = 0.f, SB = 0.f;
#pragma unroll
        for (int c = 0; c < NCTX; c++) A[c] = 0.f;
        const float* qp = Qt + ((size_t)bh * DQ + d0) * NT + t;
        const float* kp = Kt + ((size_t)bh * DQ + d0) * NT + (t - (NCTX - 1));
        for (int d = 0; d < 52; d++) {
            float gq = g_Q[d0 + d], bq = be_Q[d0 + d];
            float gk = g_K[d0 + d], bk = be_K[d0 + d];
            float qln = (qp[(size_t)d * NT] * rsq + mq) * gq + bq;
            float qg = qln * gk;
            SG += qg; SB += qln * bk;
            const float* kr = kp + (size_t)d * NT;
#pragma unroll
            for (int c = 0; c < NCTX; c++) A[c] += qg * kr[c];
        }
#pragma unroll
        for (int c = 0; c < NCTX; c++) s[c] = rkc[c] * A[c] + mkc[c] * SG + SB;
    } else {
#pragma unroll
        for (int c = 0; c < NCTX; c++) s[c] = 0.f;
        for (int d = 0; d < 52; d++) {
            float gq = g_Q[d0 + d], bq = be_Q[d0 + d];
            float gk = g_K[d0 + d], bk = be_K[d0 + d];
            float qln = (Qt[((size_t)bh * DQ + d0 + d) * NT + t] * rsq + mq) * gq + bq;
#pragma unroll
            for (int c = 0; c < NCTX; c++) {
                int tc = t + c;
                float kv;
                if (tc < NCTX - 1) {
                    kv = Kbuf[((size_t)bh * (NCTX - 1) + tc) * DQ + d0 + d];
                } else {
                    int tk = tc - (NCTX - 1);
                    float rk = murs[RK + bh * NT + tk];
                    float mk = murs[MK + bh * NT + tk];
                    kv = (Kt[((size_t)bh * DQ + d0 + d) * NT + tk] - mk) * rk * gk + bk;
                }
                s[c] += qln * kv;
            }
        }
    }
#pragma unroll
    for (int c = 0; c < NCTX; c++)
        spart[(size_t)((z * 32 + bh) * NCTX + c) * NT + t] = s[c];
}

// ---------------- combine + softmax: p[bh][c][t] ----------------
__global__ __launch_bounds__(256) void softmax_k(const float* __restrict__ spart,
    float* __restrict__ p)
{
    int bh = blockIdx.x;
    int t = blockIdx.y * 256 + threadIdx.x;
    if (t >= NT) return;
    float s[NCTX];
#pragma unroll
    for (int c = 0; c < NCTX; c++) s[c] = 0.f;
    for (int z = 0; z < 5; z++) {
#pragma unroll
        for (int c = 0; c < NCTX; c++)
            s[c] += spart[(size_t)((z * 32 + bh) * NCTX + c) * NT + t];
    }
    const float sc = 0.06201736729460423f; // 1/sqrt(260)
    float m = -1e30f;
#pragma unroll
    for (int c = 0; c < NCTX; c++) { s[c] *= sc; m = fmaxf(m, s[c]); }
    float den = 0.f;
#pragma unroll
    for (int c = 0; c < NCTX; c++) { s[c] = __expf(s[c] - m); den += s[c]; }
    float iden = 1.0f / den;
#pragma unroll
    for (int c = 0; c < NCTX; c++) p[(size_t)(bh * NCTX + c) * NT + t] = s[c] * iden;
}

// ---------------- Vo (LN-V fused): VoT[bh][d][t] ----------------
__global__ __launch_bounds__(256) void vo_k(const float* __restrict__ p,
    const float* __restrict__ Vt, const float* __restrict__ Vbuf,
    const float* __restrict__ murs,
    const float* __restrict__ g_V, const float* __restrict__ be_V,
    float* __restrict__ VoT)
{
    int bh = blockIdx.x;
    int t = blockIdx.y * 256 + threadIdx.x;
    if (t >= NT) return;
    int d0 = blockIdx.z * 80;
    float pc[NCTX];
#pragma unroll
    for (int c = 0; c < NCTX; c++) pc[c] = p[(size_t)(bh * NCTX + c) * NT + t];
    if (t >= NCTX - 1) {
        float prs[NCTX], Cm = 0.f, Cp = 0.f;
#pragma unroll
        for (int c = 0; c < NCTX; c++) {
            int tv = t - (NCTX - 1) + c;
            float rs = murs[RV + bh * NT + tv];
            prs[c] = pc[c] * rs;
            Cm += pc[c] * (-murs[MV + bh * NT + tv] * rs);
            Cp += pc[c];
        }
        const float* vp = Vt + ((size_t)bh * DV + d0) * NT + (t - (NCTX - 1));
        float* op = VoT + ((size_t)bh * DV + d0) * NT + t;
        for (int d = 0; d < 80; d++) {
            float gv = g_V[d0 + d], bv = be_V[d0 + d];
            const float* vr = vp + (size_t)d * NT;
            float A = 0.f;
#pragma unroll
            for (int c = 0; c < NCTX; c++) A += prs[c] * vr[c];
            op[(size_t)d * NT] = gv * (A + Cm) + bv * Cp;
        }
    } else {
        for (int d = 0; d < 80; d++) {
            float gv = g_V[d0 + d], bv = be_V[d0 + d];
            float acc = 0.f;
#pragma unroll
            for (int c = 0; c < NCTX; c++) {
                int tc = t + c;
                float v;
                if (tc < NCTX - 1) {
                    v = Vbuf[((size_t)bh * (NCTX - 1) + tc) * DV + d0 + d];
                } else {
                    int tv = tc - (NCTX - 1);
                    float rs = murs[RV + bh * NT + tv];
                    float mu = murs[MV + bh * NT + tv];
                    v = (Vt[((size_t)bh * DV + d0 + d) * NT + tv] - mu) * rs * gv + bv;
                }
                acc += pc[c] * v;
            }
            VoT[((size_t)bh * DV + d0 + d) * NT + t] = acc;
        }
    }
}

// ---------------- apply final LN + residual, output [b][o][f][t] ----------------
__global__ __launch_bounds__(256) void lnp_apply(const float* __restrict__ yraw,
    const float* __restrict__ x, const float* __restrict__ g, const float* __restrict__ be,
    const float* __restrict__ muA, const float* __restrict__ rstdA, float* __restrict__ out)
{
    int bo = blockIdx.x; int b = bo >> 7, o = bo & 127;
    int t = blockIdx.y * 256 + threadIdx.x;
    if (t >= NT) return;
    float mu = muA[b * NT + t], rstd = rstdA[b * NT + t];
    for (int f = 0; f < NF; f++) {
        size_t idx = (size_t)((b * NC + o) * NF + f) * NT + t;
        int i = f * NC + o;
        float v = yraw[idx];
        out[idx] = (v - mu) * rstd * g[i] + be[i] + x[idx];
    }
}

extern "C" void kernel_launch(void* const* d_in, const int* in_sizes, int n_in,
                              void* d_out, int out_size, void* d_ws, size_t ws_size,
                              hipStream_t stream) {
    const float* x    = (const float*)d_in[0];
    const float* mc   = (const float*)d_in[1];
    const float* Kbuf = (const float*)d_in[2];
    const float* Vbuf = (const float*)d_in[3];
    const float* W_Q  = (const float*)d_in[4];
    const float* b_Q  = (const float*)d_in[5];
    const float* a_Q  = (const float*)d_in[6];
    const float* g_Q  = (const float*)d_in[7];
    const float* be_Q = (const float*)d_in[8];
    const float* W_K  = (const float*)d_in[9];
    const float* b_K  = (const float*)d_in[10];
    const float* a_K  = (const float*)d_in[11];
    const float* g_K  = (const float*)d_in[12];
    const float* be_K = (const float*)d_in[13];
    const float* W_V  = (const float*)d_in[14];
    const float* b_V  = (const float*)d_in[15];
    const float* a_V  = (const float*)d_in[16];
    const float* g_V  = (const float*)d_in[17];
    const float* be_V = (const float*)d_in[18];
    const float* W_P  = (const float*)d_in[19];
    const float* b_P  = (const float*)d_in[20];
    const float* a_P  = (const float*)d_in[21];
    const float* g_P  = (const float*)d_in[22];
    const float* be_P = (const float*)d_in[23];

    float* out  = (float*)d_out;                       // (4,128,65,500)
    float* outK = out + (size_t)NB * NC * NF * NT;
    float* outV = outK + 32 * 9 * DQ;

    // QKV LN stats + mu/rs live in the head of d_out (dead until lnp_apply,
    // which is the last reader-free writer of the whole out region).
    float* stats = out;            // [sQ s2Q sK s2K sV s2V] : 96000 floats
    float* murs  = out + 96000;    // [muQ rsQ muK rsK muV rsV] : 96000 floats

    float* ws = (float*)d_ws;
    float* Qt   = ws;                                  // 4,160,000
    float* Kt   = Qt + (size_t)32 * DQ * NT;           // 4,160,000
    float* Vt   = Kt + (size_t)32 * DQ * NT;           // 16,640,000
    float* VoT  = Vt + (size_t)32 * DV * NT;           // 16,640,000
    float* pbuf = VoT + (size_t)32 * DV * NT;          // 160,000
    float* sP   = pbuf + (size_t)32 * NCTX * NT;       // 2,000
    float* s2P  = sP + NB * NT;                        // 2,000
    float* muP  = s2P + NB * NT;                       // 2,000
    float* rsP  = muP + NB * NT;                       // 2,000
    float* yraw  = Vt;   // alias: Vt dead after vo_k/copybuf
    float* spart = VoT;  // alias: consumed by softmax before vo_k writes VoT

    dim3 blk(256);
    const int TCH = (NT + 255) / 256;  // 2

    hipMemsetAsync(stats, 0, 96000 * sizeof(float), stream);
    hipMemsetAsync(sP, 0, 2 * NB * NT * sizeof(float), stream);

    proj32_k<<<dim3(NB * NF), blk, 0, stream>>>(x,  W_Q, b_Q, a_Q, Qt,
                                                stats + 0,     stats + 16000);
    proj32_k<<<dim3(NB * NF), blk, 0, stream>>>(mc, W_K, b_K, a_K, Kt,
                                                stats + 32000, stats + 48000);
    projV_k <<<dim3(NB * NF, 2), blk, 0, stream>>>(mc, W_V, b_V, a_V, Vt,
                                                   stats + 64000, stats + 80000);

    finqkv_k<<<dim3(188), blk, 0, stream>>>(stats, murs);

    int nbuf = 32 * 9 * DQ + 32 * 9 * DV;
    copybuf_k<<<dim3((nbuf + 255) / 256), blk, 0, stream>>>(Kt, Vt, murs,
                                                            g_K, be_K, g_V, be_V, outK, outV);

    scores_s1_k<<<dim3(32, TCH, 5), blk, 0, stream>>>(Qt, Kt, Kbuf, murs,
                                                      g_Q, be_Q, g_K, be_K, spart);
    softmax_k  <<<dim3(32, TCH), blk, 0, stream>>>(spart, pbuf);
    vo_k       <<<dim3(32, TCH, 13), blk, 0, stream>>>(pbuf, Vt, Vbuf, murs,
                                                       g_V, be_V, VoT);

    projP_k<<<dim3(NB * NF, 2), blk, 0, stream>>>(VoT, W_P, b_P, a_P, yraw, sP, s2P);

    finp_k<<<dim3((NB * NT + 255) / 256), blk, 0, stream>>>(sP, s2P, muP, rsP);

    lnp_apply<<<dim3(NB * NC, TCH), blk, 0, stream>>>(yraw, x, g_P, be_P, muP, rsP, out);
}

// Round 4
// 821.369 us; speedup vs baseline: 1.9523x; 1.9523x over previous
//
#include <hip/hip_runtime.h>
#include <math.h>

#define NB   4
#define NT   500
#define NF   65
#define NC   128
#define NH   8
#define NE   4
#define NV   16
#define NCTX 10
#define DQ   260    // NF*NE
#define DV   1040   // NF*NV
#define DP   8320   // NF*NC

// murs layout offsets (floats): [muQ rsQ muK rsK muV rsV], each 32*500
#define MQ 0
#define RQ 16000
#define MK 32000
#define RK 48000
#define MV 64000
#define RV 80000

// ---------------- Q/K projection: 128 -> 32, PReLU, [bh][d=f*4+e][t]; atomic LN stats ----------------
// Block: 32 o x 128 t; thread: 8 o x 2 t. Weights staged transposed [c][o] in LDS.
__global__ __launch_bounds__(256, 4) void proj32_k(const float* __restrict__ x,
    const float* __restrict__ W, const float* __restrict__ bias,
    const float* __restrict__ a, float* __restrict__ out,
    float* __restrict__ sS, float* __restrict__ sS2)
{
    __shared__ float Wl[NC * 32];
    int b = blockIdx.x / NF, f = blockIdx.x % NF;
    for (int idx = threadIdx.x; idx < 32 * NC; idx += 256) {
        int o = idx & 31, c = idx >> 5;
        Wl[c * 32 + o] = W[o * NC + c];
    }
    __syncthreads();
    int og = threadIdx.x >> 6;          // 0..3 -> 8 o each (one wave per og)
    int tg = threadIdx.x & 63;          // 0..63 -> 2 t each
    int t0 = blockIdx.y * 128 + tg * 2;
    int t0c = t0 <= NT - 2 ? t0 : NT - 2;
    const float* xp = x + ((size_t)(b * NC) * NF + f) * NT + t0c;
    const float* wp = Wl + og * 8;
    float2 acc[8];
#pragma unroll
    for (int i = 0; i < 8; i++) acc[i] = make_float2(0.f, 0.f);
#pragma unroll 4
    for (int c = 0; c < NC; c++) {
        float2 xv = *(const float2*)(xp + (size_t)c * (NF * NT));
        const float* wc = wp + c * 32;
        float wv[8];
        *(float4*)(wv)     = *(const float4*)(wc);
        *(float4*)(wv + 4) = *(const float4*)(wc + 4);
#pragma unroll
        for (int i = 0; i < 8; i++) {
            acc[i].x += xv.x * wv[i];
            acc[i].y += xv.y * wv[i];
        }
    }
    if (t0 > NT - 2) return;
    float av = a[0];
#pragma unroll
    for (int i = 0; i < 8; i++) {
        int o = og * 8 + i;
        float vx = acc[i].x + bias[o], vy = acc[i].y + bias[o];
        vx = vx >= 0.f ? vx : av * vx;
        vy = vy >= 0.f ? vy : av * vy;
        acc[i].x = vx; acc[i].y = vy;
        int h = o >> 2, e = o & 3;
        *(float2*)(out + ((size_t)(b * NH + h) * DQ + f * NE + e) * NT + t0) = acc[i];
    }
#pragma unroll
    for (int hh = 0; hh < 2; hh++) {
        int h = og * 2 + hh;
        float sx = 0.f, sy = 0.f, qx = 0.f, qy = 0.f;
#pragma unroll
        for (int e = 0; e < 4; e++) {
            float2 v = acc[hh * 4 + e];
            sx += v.x; sy += v.y; qx += v.x * v.x; qy += v.y * v.y;
        }
        int base = (b * NH + h) * NT + t0;
        atomicAdd(&sS[base], sx);      atomicAdd(&sS[base + 1], sy);
        atomicAdd(&sS2[base], qx);     atomicAdd(&sS2[base + 1], qy);
    }
}

// ---------------- V projection: 128 -> 128 (64 o / block), PReLU, [bh][d=f*16+v][t]; atomic LN stats ----------------
// Block: 64 o x 128 t; thread: 16 o x 2 t.
__global__ __launch_bounds__(256, 4) void projV_k(const float* __restrict__ x,
    const float* __restrict__ W, const float* __restrict__ bias,
    const float* __restrict__ a, float* __restrict__ out,
    float* __restrict__ sS, float* __restrict__ sS2)
{
    __shared__ float Wl[NC * 64];
    int b = blockIdx.x / NF, f = blockIdx.x % NF;
    int o0 = blockIdx.z * 64;
    for (int idx = threadIdx.x; idx < 64 * NC; idx += 256) {
        int o = idx & 63, c = idx >> 6;
        Wl[c * 64 + o] = W[(o0 + o) * NC + c];
    }
    __syncthreads();
    int og = threadIdx.x >> 6;          // 0..3 -> 16 o each
    int tg = threadIdx.x & 63;
    int t0 = blockIdx.y * 128 + tg * 2;
    int t0c = t0 <= NT - 2 ? t0 : NT - 2;
    const float* xp = x + ((size_t)(b * NC) * NF + f) * NT + t0c;
    const float* wp = Wl + og * 16;
    float2 acc[16];
#pragma unroll
    for (int i = 0; i < 16; i++) acc[i] = make_float2(0.f, 0.f);
#pragma unroll 2
    for (int c = 0; c < NC; c++) {
        float2 xv = *(const float2*)(xp + (size_t)c * (NF * NT));
        const float* wc = wp + c * 64;
        float wv[16];
        *(float4*)(wv)      = *(const float4*)(wc);
        *(float4*)(wv + 4)  = *(const float4*)(wc + 4);
        *(float4*)(wv + 8)  = *(const float4*)(wc + 8);
        *(float4*)(wv + 12) = *(const float4*)(wc + 12);
#pragma unroll
        for (int i = 0; i < 16; i++) {
            acc[i].x += xv.x * wv[i];
            acc[i].y += xv.y * wv[i];
        }
    }
    if (t0 > NT - 2) return;
    float av = a[0];
    int h = (o0 >> 4) + og;             // this thread's 16 o are exactly head h
    float sx = 0.f, sy = 0.f, qx = 0.f, qy = 0.f;
#pragma unroll
    for (int i = 0; i < 16; i++) {
        int o = o0 + og * 16 + i;
        float vx = acc[i].x + bias[o], vy = acc[i].y + bias[o];
        vx = vx >= 0.f ? vx : av * vx;
        vy = vy >= 0.f ? vy : av * vy;
        *(float2*)(out + ((size_t)(b * NH + h) * DV + f * NV + i) * NT + t0) = make_float2(vx, vy);
        sx += vx; sy += vy; qx += vx * vx; qy += vy * vy;
    }
    int base = (b * NH + h) * NT + t0;
    atomicAdd(&sS[base], sx);      atomicAdd(&sS[base + 1], sy);
    atomicAdd(&sS2[base], qx);     atomicAdd(&sS2[base + 1], qy);
}

// ---------------- P projection: VoT 128 -> 128 (64 o / block), PReLU, yraw[b][o][f][t]; atomic final-LN stats ----------------
__global__ __launch_bounds__(256, 4) void projP_k(const float* __restrict__ VoT,
    const float* __restrict__ W, const float* __restrict__ bias,
    const float* __restrict__ a, float* __restrict__ yraw,
    float* __restrict__ sP, float* __restrict__ s2P)
{
    __shared__ float Wl[NC * 64];
    int b = blockIdx.x / NF, f = blockIdx.x % NF;
    int o0 = blockIdx.z * 64;
    for (int idx = threadIdx.x; idx < 64 * NC; idx += 256) {
        int o = idx & 63, c = idx >> 6;
        Wl[c * 64 + o] = W[(o0 + o) * NC + c];
    }
    __syncthreads();
    int og = threadIdx.x >> 6;
    int tg = threadIdx.x & 63;
    int t0 = blockIdx.y * 128 + tg * 2;
    int t0c = t0 <= NT - 2 ? t0 : NT - 2;
    const float* zp = VoT + ((size_t)(b * NH) * DV + f * NV) * NT + t0c;
    const float* wp = Wl + og * 16;
    float2 acc[16];
#pragma unroll
    for (int i = 0; i < 16; i++) acc[i] = make_float2(0.f, 0.f);
    for (int hc = 0; hc < NH; hc++) {
        const float* zh = zp + (size_t)hc * DV * NT;
        const float* wh = wp + hc * 16 * 64;
#pragma unroll
        for (int v = 0; v < NV; v++) {
            float2 xv = *(const float2*)(zh + (size_t)v * NT);
            const float* wc = wh + v * 64;
            float wv[16];
            *(float4*)(wv)      = *(const float4*)(wc);
            *(float4*)(wv + 4)  = *(const float4*)(wc + 4);
            *(float4*)(wv + 8)  = *(const float4*)(wc + 8);
            *(float4*)(wv + 12) = *(const float4*)(wc + 12);
#pragma unroll
            for (int i = 0; i < 16; i++) {
                acc[i].x += xv.x * wv[i];
                acc[i].y += xv.y * wv[i];
            }
        }
    }
    if (t0 > NT - 2) return;
    float av = a[0];
    float sx = 0.f, sy = 0.f, qx = 0.f, qy = 0.f;
#pragma unroll
    for (int i = 0; i < 16; i++) {
        int o = o0 + og * 16 + i;
        float vx = acc[i].x + bias[o], vy = acc[i].y + bias[o];
        vx = vx >= 0.f ? vx : av * vx;
        vy = vy >= 0.f ? vy : av * vy;
        *(float2*)(yraw + ((size_t)(b * NC + o) * NF + f) * NT + t0) = make_float2(vx, vy);
        sx += vx; sy += vy; qx += vx * vx; qy += vy * vy;
    }
    int base = b * NT + t0;
    atomicAdd(&sP[base], sx);      atomicAdd(&sP[base + 1], sy);
    atomicAdd(&s2P[base], qx);     atomicAdd(&s2P[base + 1], qy);
}

// ---------------- finalize QKV stats -> mu/rs ----------------
__global__ __launch_bounds__(256) void finqkv_k(const float* __restrict__ stats,
    float* __restrict__ murs)
{
    int i = blockIdx.x * 256 + threadIdx.x;
    if (i >= 48000) return;
    int seg = i / 16000, j = i % 16000;
    float S = stats[seg * 32000 + j], S2 = stats[seg * 32000 + 16000 + j];
    float D = (seg < 2) ? 260.f : 1040.f;
    float mu = S / D;
    float var = S2 / D - mu * mu;
    murs[seg * 32000 + j] = mu;
    murs[seg * 32000 + 16000 + j] = rsqrtf(var + 1e-5f);
}

__global__ __launch_bounds__(256) void finp_k(const float* __restrict__ sP,
    const float* __restrict__ s2P, float* __restrict__ muP, float* __restrict__ rsP)
{
    int i = blockIdx.x * 256 + threadIdx.x;
    if (i >= NB * NT) return;
    float inv = 1.0f / (float)DP;
    float mu = sP[i] * inv;
    float var = s2P[i] * inv - mu * mu;
    muP[i] = mu;
    rsP[i] = rsqrtf(var + 1e-5f);
}

// ---------------- K_buf_new / V_buf_new: LN applied on the fly ----------------
__global__ void copybuf_k(const float* __restrict__ Kt, const float* __restrict__ Vt,
    const float* __restrict__ murs,
    const float* __restrict__ g_K, const float* __restrict__ be_K,
    const float* __restrict__ g_V, const float* __restrict__ be_V,
    float* __restrict__ outK, float* __restrict__ outV)
{
    int i = blockIdx.x * 256 + threadIdx.x;
    const int NK = 32 * 9 * DQ;
    const int NVb = 32 * 9 * DV;
    if (i < NK) {
        int bh = i / (9 * DQ); int r = i % (9 * DQ); int j = r / DQ; int d = r % DQ;
        int tt = 491 + j;
        float v = Kt[(size_t)(bh * DQ + d) * NT + tt];
        float mu = murs[MK + bh * NT + tt], rs = murs[RK + bh * NT + tt];
        outK[i] = (v - mu) * rs * g_K[d] + be_K[d];
    } else if (i < NK + NVb) {
        int i2 = i - NK;
        int bh = i2 / (9 * DV); int r = i2 % (9 * DV); int j = r / DV; int d = r % DV;
        int tt = 491 + j;
        float v = Vt[(size_t)(bh * DV + d) * NT + tt];
        float mu = murs[MV + bh * NT + tt], rs = murs[RV + bh * NT + tt];
        outV[i2] = (v - mu) * rs * g_V[d] + be_V[d];
    }
}

// ---------------- scores partials (LN fused): spart[ch][bh][c][t] ----------------
__global__ __launch_bounds__(256) void scores_s1_k(const float* __restrict__ Qt,
    const float* __restrict__ Kt, const float* __restrict__ Kbuf,
    const float* __restrict__ murs,
    const float* __restrict__ g_Q, const float* __restrict__ be_Q,
    const float* __restrict__ g_K, const float* __restrict__ be_K,
    float* __restrict__ spart)
{
    int bh = blockIdx.x;
    int t = blockIdx.y * 256 + threadIdx.x;
    if (t >= NT) return;
    int z = blockIdx.z;
    int d0 = z * 52;
    float rsq = murs[RQ + bh * NT + t];
    float mq = -murs[MQ + bh * NT + t] * rsq;
    float s[NCTX];
    if (t >= NCTX - 1) {
        float rkc[NCTX], mkc[NCTX];
#pragma unroll
        for (int c = 0; c < NCTX; c++) {
            int tk = t - (NCTX - 1) + c;
            rkc[c] = murs[RK + bh * NT + tk];
            mkc[c] = -murs[MK + bh * NT + tk] * rkc[c];
        }
        float A[NCTX], SG = 0.f, SB = 0.f;
#pragma unroll
        for (int c = 0; c < NCTX; c++) A[c] = 0.f;
        const float* qp = Qt + ((size_t)bh * DQ + d0) * NT + t;
        const float* kp = Kt + ((size_t)bh * DQ + d0) * NT + (t - (NCTX - 1));
        for (int d = 0; d < 52; d++) {
            float gq = g_Q[d0 + d], bq = be_Q[d0 + d];
            float gk = g_K[d0 + d], bk = be_K[d0 + d];
            float qln = (qp[(size_t)d * NT] * rsq + mq) * gq + bq;
            float qg = qln * gk;
            SG += qg; SB += qln * bk;
            const float* kr = kp + (size_t)d * NT;
#pragma unroll
            for (int c = 0; c < NCTX; c++) A[c] += qg * kr[c];
        }
#pragma unroll
        for (int c = 0; c < NCTX; c++) s[c] = rkc[c] * A[c] + mkc[c] * SG + SB;
    } else {
#pragma unroll
        for (int c = 0; c < NCTX; c++) s[c] = 0.f;
        for (int d = 0; d < 52; d++) {
            float gq = g_Q[d0 + d], bq = be_Q[d0 + d];
            float gk = g_K[d0 + d], bk = be_K[d0 + d];
            float qln = (Qt[((size_t)bh * DQ + d0 + d) * NT + t] * rsq + mq) * gq + bq;
#pragma unroll
            for (int c = 0; c < NCTX; c++) {
                int tc = t + c;
                float kv;
                if (tc < NCTX - 1) {
                    kv = Kbuf[((size_t)bh * (NCTX - 1) + tc) * DQ + d0 + d];
                } else {
                    int tk = tc - (NCTX - 1);
                    float rk = murs[RK + bh * NT + tk];
                    float mk = murs[MK + bh * NT + tk];
                    kv = (Kt[((size_t)bh * DQ + d0 + d) * NT + tk] - mk) * rk * gk + bk;
                }
                s[c] += qln * kv;
            }
        }
    }
#pragma unroll
    for (int c = 0; c < NCTX; c++)
        spart[(size_t)((z * 32 + bh) * NCTX + c) * NT + t] = s[c];
}

// ---------------- combine + softmax: p[bh][c][t] ----------------
__global__ __launch_bounds__(256) void softmax_k(const float* __restrict__ spart,
    float* __restrict__ p)
{
    int bh = blockIdx.x;
    int t = blockIdx.y * 256 + threadIdx.x;
    if (t >= NT) return;
    float s[NCTX];
#pragma unroll
    for (int c = 0; c < NCTX; c++) s[c] = 0.f;
    for (int z = 0; z < 5; z++) {
#pragma unroll
        for (int c = 0; c < NCTX; c++)
            s[c] += spart[(size_t)((z * 32 + bh) * NCTX + c) * NT + t];
    }
    const float sc = 0.06201736729460423f; // 1/sqrt(260)
    float m = -1e30f;
#pragma unroll
    for (int c = 0; c < NCTX; c++) { s[c] *= sc; m = fmaxf(m, s[c]); }
    float den = 0.f;
#pragma unroll
    for (int c = 0; c < NCTX; c++) { s[c] = __expf(s[c] - m); den += s[c]; }
    float iden = 1.0f / den;
#pragma unroll
    for (int c = 0; c < NCTX; c++) p[(size_t)(bh * NCTX + c) * NT + t] = s[c] * iden;
}

// ---------------- Vo (LN-V fused): VoT[bh][d][t] ----------------
__global__ __launch_bounds__(256) void vo_k(const float* __restrict__ p,
    const float* __restrict__ Vt, const float* __restrict__ Vbuf,
    const float* __restrict__ murs,
    const float* __restrict__ g_V, const float* __restrict__ be_V,
    float* __restrict__ VoT)
{
    int bh = blockIdx.x;
    int t = blockIdx.y * 256 + threadIdx.x;
    if (t >= NT) return;
    int d0 = blockIdx.z * 80;
    float pc[NCTX];
#pragma unroll
    for (int c = 0; c < NCTX; c++) pc[c] = p[(size_t)(bh * NCTX + c) * NT + t];
    if (t >= NCTX - 1) {
        float prs[NCTX], Cm = 0.f, Cp = 0.f;
#pragma unroll
        for (int c = 0; c < NCTX; c++) {
            int tv = t - (NCTX - 1) + c;
            float rs = murs[RV + bh * NT + tv];
            prs[c] = pc[c] * rs;
            Cm += pc[c] * (-murs[MV + bh * NT + tv] * rs);
            Cp += pc[c];
        }
        const float* vp = Vt + ((size_t)bh * DV + d0) * NT + (t - (NCTX - 1));
        float* op = VoT + ((size_t)bh * DV + d0) * NT + t;
        for (int d = 0; d < 80; d++) {
            float gv = g_V[d0 + d], bv = be_V[d0 + d];
            const float* vr = vp + (size_t)d * NT;
            float A = 0.f;
#pragma unroll
            for (int c = 0; c < NCTX; c++) A += prs[c] * vr[c];
            op[(size_t)d * NT] = gv * (A + Cm) + bv * Cp;
        }
    } else {
        for (int d = 0; d < 80; d++) {
            float gv = g_V[d0 + d], bv = be_V[d0 + d];
            float acc = 0.f;
#pragma unroll
            for (int c = 0; c < NCTX; c++) {
                int tc = t + c;
                float v;
                if (tc < NCTX - 1) {
                    v = Vbuf[((size_t)bh * (NCTX - 1) + tc) * DV + d0 + d];
                } else {
                    int tv = tc - (NCTX - 1);
                    float rs = murs[RV + bh * NT + tv];
                    float mu = murs[MV + bh * NT + tv];
                    v = (Vt[((size_t)bh * DV + d0 + d) * NT + tv] - mu) * rs * gv + bv;
                }
                acc += pc[c] * v;
            }
            VoT[((size_t)bh * DV + d0 + d) * NT + t] = acc;
        }
    }
}

// ---------------- apply final LN + residual, output [b][o][f][t] ----------------
__global__ __launch_bounds__(256) void lnp_apply(const float* __restrict__ yraw,
    const float* __restrict__ x, const float* __restrict__ g, const float* __restrict__ be,
    const float* __restrict__ muA, const float* __restrict__ rstdA, float* __restrict__ out)
{
    int bo = blockIdx.x; int b = bo >> 7, o = bo & 127;
    int t = blockIdx.y * 256 + threadIdx.x;
    if (t >= NT) return;
    float mu = muA[b * NT + t], rstd = rstdA[b * NT + t];
    for (int f = 0; f < NF; f++) {
        size_t idx = (size_t)((b * NC + o) * NF + f) * NT + t;
        int i = f * NC + o;
        float v = yraw[idx];
        out[idx] = (v - mu) * rstd * g[i] + be[i] + x[idx];
    }
}

extern "C" void kernel_launch(void* const* d_in, const int* in_sizes, int n_in,
                              void* d_out, int out_size, void* d_ws, size_t ws_size,
                              hipStream_t stream) {
    const float* x    = (const float*)d_in[0];
    const float* mc   = (const float*)d_in[1];
    const float* Kbuf = (const float*)d_in[2];
    const float* Vbuf = (const float*)d_in[3];
    const float* W_Q  = (const float*)d_in[4];
    const float* b_Q  = (const float*)d_in[5];
    const float* a_Q  = (const float*)d_in[6];
    const float* g_Q  = (const float*)d_in[7];
    const float* be_Q = (const float*)d_in[8];
    const float* W_K  = (const float*)d_in[9];
    const float* b_K  = (const float*)d_in[10];
    const float* a_K  = (const float*)d_in[11];
    const float* g_K  = (const float*)d_in[12];
    const float* be_K = (const float*)d_in[13];
    const float* W_V  = (const float*)d_in[14];
    const float* b_V  = (const float*)d_in[15];
    const float* a_V  = (const float*)d_in[16];
    const float* g_V  = (const float*)d_in[17];
    const float* be_V = (const float*)d_in[18];
    const float* W_P  = (const float*)d_in[19];
    const float* b_P  = (const float*)d_in[20];
    const float* a_P  = (const float*)d_in[21];
    const float* g_P  = (const float*)d_in[22];
    const float* be_P = (const float*)d_in[23];

    float* out  = (float*)d_out;                       // (4,128,65,500)
    float* outK = out + (size_t)NB * NC * NF * NT;
    float* outV = outK + 32 * 9 * DQ;

    // QKV LN stats + mu/rs live in the head of d_out (dead until lnp_apply).
    float* stats = out;            // [sQ s2Q sK s2K sV s2V] : 96000 floats
    float* murs  = out + 96000;    // [muQ rsQ muK rsK muV rsV] : 96000 floats

    float* ws = (float*)d_ws;
    float* Qt   = ws;                                  // 4,160,000
    float* Kt   = Qt + (size_t)32 * DQ * NT;           // 4,160,000
    float* Vt   = Kt + (size_t)32 * DQ * NT;           // 16,640,000
    float* VoT  = Vt + (size_t)32 * DV * NT;           // 16,640,000
    float* pbuf = VoT + (size_t)32 * DV * NT;          // 160,000
    float* sP   = pbuf + (size_t)32 * NCTX * NT;       // 2,000
    float* s2P  = sP + NB * NT;                        // 2,000
    float* muP  = s2P + NB * NT;                       // 2,000
    float* rsP  = muP + NB * NT;                       // 2,000
    float* yraw  = Vt;   // alias: Vt dead after vo_k/copybuf
    float* spart = VoT;  // alias: consumed by softmax before vo_k writes VoT

    dim3 blk(256);
    const int TCH = (NT + 255) / 256;  // 2

    hipMemsetAsync(stats, 0, 96000 * sizeof(float), stream);
    hipMemsetAsync(sP, 0, 2 * NB * NT * sizeof(float), stream);

    proj32_k<<<dim3(NB * NF, 4), blk, 0, stream>>>(x,  W_Q, b_Q, a_Q, Qt,
                                                   stats + 0,     stats + 16000);
    proj32_k<<<dim3(NB * NF, 4), blk, 0, stream>>>(mc, W_K, b_K, a_K, Kt,
                                                   stats + 32000, stats + 48000);
    projV_k <<<dim3(NB * NF, 4, 2), blk, 0, stream>>>(mc, W_V, b_V, a_V, Vt,
                                                      stats + 64000, stats + 80000);

    finqkv_k<<<dim3(188), blk, 0, stream>>>(stats, murs);

    int nbuf = 32 * 9 * DQ + 32 * 9 * DV;
    copybuf_k<<<dim3((nbuf + 255) / 256), blk, 0, stream>>>(Kt, Vt, murs,
                                                            g_K, be_K, g_V, be_V, outK, outV);

    scores_s1_k<<<dim3(32, TCH, 5), blk, 0, stream>>>(Qt, Kt, Kbuf, murs,
                                                      g_Q, be_Q, g_K, be_K, spart);
    softmax_k  <<<dim3(32, TCH), blk, 0, stream>>>(spart, pbuf);
    vo_k       <<<dim3(32, TCH, 13), blk, 0, stream>>>(pbuf, Vt, Vbuf, murs,
                                                       g_V, be_V, VoT);

    projP_k<<<dim3(NB * NF, 4, 2), blk, 0, stream>>>(VoT, W_P, b_P, a_P, yraw, sP, s2P);

    finp_k<<<dim3((NB * NT + 255) / 256), blk, 0, stream>>>(sP, s2P, muP, rsP);

    lnp_apply<<<dim3(NB * NC, TCH), blk, 0, stream>>>(yraw, x, g_P, be_P, muP, rsP, out);
}